// Round 6
// baseline (272.616 us; speedup 1.0000x reference)
//
#include <hip/hip_runtime.h>
#include <hip/hip_bf16.h>

// Problem constants
#define B_  16
#define L_  1024
#define F_  512
#define H_  8
#define D_  64
#define M_  (B_ * L_)    // 16384 rows
#define HD_ 512

typedef __bf16 bf16x8 __attribute__((ext_vector_type(8)));
typedef __bf16 bf16x4 __attribute__((ext_vector_type(4)));
typedef short  s16x4  __attribute__((ext_vector_type(4)));
typedef float  f32x4  __attribute__((ext_vector_type(4)));

// Async global->LDS, 16B per lane. LDS dest must be wave-uniform base + lane*16.
__device__ __forceinline__ void gl_lds16(const void* g, void* l) {
  __builtin_amdgcn_global_load_lds(
      (const __attribute__((address_space(1))) unsigned int*)g,
      (__attribute__((address_space(3))) unsigned int*)l, 16, 0, 0);
}

#define WAIT_VM_LG(N)                                                           \
  asm volatile("s_waitcnt vmcnt(" #N ") lgkmcnt(0)" ::: "memory")
#define BARRIER() asm volatile("s_barrier" ::: "memory")

// ---------------------------------------------------------------------------
// Weight prep: Wt[n][k] = (bf16) W[k][n]  for Wq,Wk,Wv,Wo (each 512x512).
// ---------------------------------------------------------------------------
__global__ __launch_bounds__(256) void wt_kernel(
    const float* __restrict__ Wq, const float* __restrict__ Wk,
    const float* __restrict__ Wv, const float* __restrict__ Wo,
    __bf16* __restrict__ Wt_all)
{
  const float* W = (blockIdx.z == 0) ? Wq : (blockIdx.z == 1) ? Wk
                 : (blockIdx.z == 2) ? Wv : Wo;
  __bf16* Wt = Wt_all + (size_t)blockIdx.z * (512 * 512);
  __shared__ float s[32][33];
  const int t = threadIdx.x;
  const int r = t >> 5, c = t & 31;
  const int k0 = blockIdx.x * 32, n0 = blockIdx.y * 32;
#pragma unroll
  for (int i = 0; i < 4; ++i)
    s[r + i * 8][c] = W[(size_t)(k0 + r + i * 8) * 512 + n0 + c];
  __syncthreads();
#pragma unroll
  for (int i = 0; i < 4; ++i)
    Wt[(size_t)(n0 + r + i * 8) * 512 + k0 + c] = (__bf16)s[c][r + i * 8];
}

// ---------------------------------------------------------------------------
// Merged projection GEMM (q, k, v). 128x128 tile, 256 thr.
// A: fp32 load->reg (distance 1) -> convert -> ds_write (double-buffered).
// B: async DMA, TRIPLE-buffered, prefetch distance 2, counted vmcnt — the
// B-DMA queue is never drained to 0 inside the loop.
// by = blockIdx.y + ybase; seg = by>>2 (0 q, 1 k, 2 v); n0 = (by&3)*128.
// seg 0/1 dst (B,H,L,D); seg 2 dst (B,H,D,L).
// ---------------------------------------------------------------------------
__global__ __launch_bounds__(256) void gemm_proj_kernel(
    const float* __restrict__ Xq, const float* __restrict__ Xkv,
    const __bf16* __restrict__ Wt_all,
    const float* __restrict__ bq, const float* __restrict__ bk_,
    const float* __restrict__ bv_,
    __bf16* __restrict__ qd, __bf16* __restrict__ kd, __bf16* __restrict__ vd,
    int ybase)
{
  const int by = blockIdx.y + ybase;
  const int seg = by >> 2;
  const float* X = (seg == 0) ? Xq : Xkv;
  const __bf16* Wt = Wt_all + (size_t)seg * 262144;
  const float* bias = (seg == 0) ? bq : (seg == 1) ? bk_ : bv_;
  __bf16* dst = (seg == 0) ? qd : (seg == 1) ? kd : vd;
  const int mode = seg;

  __shared__ __align__(16) __bf16 As[2][4][128][8];  // 16 KB
  __shared__ __align__(16) __bf16 Bs[3][4][128][8];  // 24 KB
  const int t = threadIdx.x;
  const int m0 = blockIdx.x * 128, n0 = (by & 3) * 128;
  const int lane = t & 63, w = t >> 6;
  const int ml = lane & 15, quad = lane >> 4;
  const int wm = w & 1, wn = w >> 1;

  f32x4 acc[4][4];
#pragma unroll
  for (int i = 0; i < 4; ++i)
#pragma unroll
    for (int j = 0; j < 4; ++j) acc[i][j] = (f32x4){0.f, 0.f, 0.f, 0.f};

  // A slots: 2 per thread (512 slots of 8 elems cover 128x32)
  const int ako0 = t & 3,          arow0 = t >> 2;
  const int ako1 = (t + 256) & 3,  arow1 = (t + 256) >> 2;
  // B DMA slots: 2 per thread, wave-uniform LDS dest
  const int bs0 = w * 64 + lane,   bs1 = (w + 4) * 64 + lane;
  const int bko0 = bs0 >> 7, brow0 = bs0 & 127;
  const int bko1 = bs1 >> 7, brow1 = bs1 & 127;

  float4 fa0, fa1, fa2, fa3;  // A prefetch registers (16 fp32)

#define ALOAD(kk)                                                               \
  do {                                                                          \
    const float* p0 = X + (size_t)(m0 + arow0) * 512 + (kk) + ako0 * 8;         \
    const float* p1 = X + (size_t)(m0 + arow1) * 512 + (kk) + ako1 * 8;         \
    fa0 = *(const float4*)p0; fa1 = *(const float4*)(p0 + 4);                   \
    fa2 = *(const float4*)p1; fa3 = *(const float4*)(p1 + 4);                   \
  } while (0)

#define AWRITE(buf)                                                             \
  do {                                                                          \
    bf16x8 v0, v1;                                                              \
    v0[0] = (__bf16)fa0.x; v0[1] = (__bf16)fa0.y; v0[2] = (__bf16)fa0.z;        \
    v0[3] = (__bf16)fa0.w; v0[4] = (__bf16)fa1.x; v0[5] = (__bf16)fa1.y;        \
    v0[6] = (__bf16)fa1.z; v0[7] = (__bf16)fa1.w;                               \
    v1[0] = (__bf16)fa2.x; v1[1] = (__bf16)fa2.y; v1[2] = (__bf16)fa2.z;        \
    v1[3] = (__bf16)fa2.w; v1[4] = (__bf16)fa3.x; v1[5] = (__bf16)fa3.y;        \
    v1[6] = (__bf16)fa3.z; v1[7] = (__bf16)fa3.w;                               \
    *(bf16x8*)&As[buf][ako0][arow0][0] = v0;                                    \
    *(bf16x8*)&As[buf][ako1][arow1][0] = v1;                                    \
  } while (0)

#define BSTAGE(buf, kk)                                                         \
  do {                                                                          \
    gl_lds16(&Wt[(size_t)(n0 + brow0) * 512 + (kk) + bko0 * 8],                 \
             &Bs[buf][bko0][brow0][0]);                                         \
    gl_lds16(&Wt[(size_t)(n0 + brow1) * 512 + (kk) + bko1 * 8],                 \
             &Bs[buf][bko1][brow1][0]);                                         \
  } while (0)

#define COMPUTE_TILE(ab, bb)                                                    \
  do {                                                                          \
    bf16x8 a[4], b[4];                                                          \
    _Pragma("unroll") for (int mt = 0; mt < 4; ++mt)                            \
        a[mt] = *(const bf16x8*)&As[ab][quad][wm * 64 + mt * 16 + ml][0];       \
    _Pragma("unroll") for (int nt = 0; nt < 4; ++nt)                            \
        b[nt] = *(const bf16x8*)&Bs[bb][quad][wn * 64 + nt * 16 + ml][0];       \
    _Pragma("unroll") for (int mt = 0; mt < 4; ++mt)                            \
        _Pragma("unroll") for (int nt = 0; nt < 4; ++nt)                        \
            acc[mt][nt] = __builtin_amdgcn_mfma_f32_16x16x32_bf16(              \
                a[mt], b[nt], acc[mt][nt], 0, 0, 0);                            \
  } while (0)

  // prologue: A(0) -> As[0]; B(0),B(1) staged (B(1) stays in flight)
  ALOAD(0);
  BSTAGE(0, 0);
  BSTAGE(1, 32);
  AWRITE(0);                 // compiler waits the A loads (older than B DMAs)
  WAIT_VM_LG(2);             // B(0) done; ds_writes flushed. B(1) in flight.
  BARRIER();

  int bcur = 0, bst = 2;
  for (int tt = 0; tt < 16; ++tt) {
    if (tt < 15) ALOAD((tt + 1) * 32);
    if (tt < 14) BSTAGE(bst, (tt + 2) * 32);
    COMPUTE_TILE(tt & 1, bcur);
    if (tt < 14) {
      WAIT_VM_LG(2);         // A(tt+1) + B(tt+1) done; B(tt+2) stays in flight
      AWRITE((tt + 1) & 1);
      asm volatile("s_waitcnt lgkmcnt(0)" ::: "memory");
      BARRIER();
    } else if (tt == 14) {
      WAIT_VM_LG(0);         // last A; queue empty entering final tile
      AWRITE((tt + 1) & 1);
      asm volatile("s_waitcnt lgkmcnt(0)" ::: "memory");
      BARRIER();
    }
    bcur = (bcur == 2) ? 0 : bcur + 1;
    bst = (bst == 2) ? 0 : bst + 1;
  }

#pragma unroll
  for (int nt = 0; nt < 4; ++nt) {
    int col = n0 + wn * 64 + nt * 16 + ml;
    float bv = bias[col];
    int h = col >> 6, d = col & 63;
#pragma unroll
    for (int mt = 0; mt < 4; ++mt) {
      int row0 = m0 + wm * 64 + mt * 16 + quad * 4;
      int bz = row0 >> 10;
      int l0 = row0 & 1023;
      if (mode == 2) {
        bf16x4 pk;
#pragma unroll
        for (int r = 0; r < 4; ++r) pk[r] = (__bf16)(acc[mt][nt][r] + bv);
        size_t idx = ((size_t)(bz * H_ + h) * D_ + d) * L_ + l0;
        *(bf16x4*)&dst[idx] = pk;
      } else {
        size_t base = ((size_t)(bz * H_ + h) * L_ + l0) * D_ + d;
#pragma unroll
        for (int r = 0; r < 4; ++r)
          dst[base + (size_t)r * D_] = (__bf16)(acc[mt][nt][r] + bv);
      }
    }
  }
#undef ALOAD
#undef AWRITE
#undef BSTAGE
#undef COMPUTE_TILE
}

// ---------------------------------------------------------------------------
// Flash attention v7: v6 + TRIPLE-buffered K/V with prefetch distance 2 and
// counted vmcnt (the old __syncthreads drained the just-issued prefetch to 0
// at every tile -> exposed load latency at all 16 barriers), + exp2 with
// log2e pre-folded into the LDS toeplitz copy (kills one v_mul per element).
// LDS = 16 (toep) + 3x8 (K) + 3x8 (V) = 64 KB -> 2 blocks/CU.
// ---------------------------------------------------------------------------
__global__ __launch_bounds__(256, 2) void attn_kernel(
    const __bf16* __restrict__ qg,    // [B][H][L][D]
    const __bf16* __restrict__ kg,    // [B][H][L][D]
    const __bf16* __restrict__ vg,    // [B][H][D][L]
    const float* __restrict__ toep_g, // [H][4096]
    __bf16* __restrict__ xg)          // [B*L][512]
{
  __shared__ float toep[4096];                   // 16 KB (pre-scaled by log2e)
  __shared__ __align__(16) __bf16 Ks[3][64][64]; // 3 x 8 KB (swizzled)
  __shared__ __align__(16) __bf16 Vs[3][64][64]; // 3 x 8 KB (swizzled)

  const int t = threadIdx.x;
  const int n = blockIdx.x;
  // XCD swizzle: the 4 q-tiles sharing one (b,h) land on the same XCD.
  const int bh = ((n >> 5) << 3) | (n & 7);
  const int q0 = ((n >> 3) & 3) * 256;
  const int h = bh & 7;
  const int lane = t & 63, w = t >> 6;
  const int ml = lane & 15, quad = lane >> 4;
  const int lo3 = lane >> 3;        // 0..7 (== row&7 for staging rows)
  const int kop = lane & 7;         // LDS 16B-chunk slot

  const size_t qkbase = (size_t)bh * (L_ * D_);
  const size_t vbase  = (size_t)bh * (D_ * L_);

  // toeplitz table -> LDS, pre-multiplied by log2(e) for the exp2 path
  {
    const float4* src = (const float4*)(toep_g + (size_t)h * 4096);
    float4* dl = (float4*)toep;
    for (int i = t; i < 1024; i += 256) {
      float4 v = src[i];
      v.x *= 1.44269504f; v.y *= 1.44269504f;
      v.z *= 1.44269504f; v.w *= 1.44269504f;
      dl[i] = v;
    }
  }

#define KV_STAGE(buf, k0n)                                                      \
  do {                                                                          \
    _Pragma("unroll") for (int i = 0; i < 2; ++i) {                             \
      int row = (w * 2 + i) * 8 + lo3;                                          \
      int ko = kop ^ lo3;                                                       \
      gl_lds16(&kg[qkbase + (size_t)((k0n) + row) * D_ + ko * 8],               \
               &Ks[buf][row][kop * 8]);                                         \
      gl_lds16(&vg[vbase + (size_t)row * L_ + (k0n) + ko * 8],                  \
               &Vs[buf][row][kop * 8]);                                         \
    }                                                                           \
  } while (0)

  // stage tiles 0,1 (8 DMA; tile-1's 4 stay in flight across the first wait)
  KV_STAGE(0, 0);
  KV_STAGE(1, 64);

  // Q B-fragments, 4 q-subtiles, registers for the whole kernel (32 VGPR)
  bf16x8 qf[4][2];
#pragma unroll
  for (int qn = 0; qn < 4; ++qn) {
    const __bf16* qp =
        qg + qkbase + (size_t)(q0 + w * 64 + qn * 16 + ml) * D_ + quad * 8;
    qf[qn][0] = *(const bf16x8*)qp;
    qf[qn][1] = *(const bf16x8*)(qp + 32);
  }

  float lpart[4] = {0.f, 0.f, 0.f, 0.f};
  f32x4 o[4][4];
#pragma unroll
  for (int qn = 0; qn < 4; ++qn)
#pragma unroll
    for (int dt = 0; dt < 4; ++dt) o[qn][dt] = (f32x4){0.f, 0.f, 0.f, 0.f};

  // One K-tile of work: tc register cache + 4x 16-key groups (S^T->exp2->PV)
#define ATTN_TILE(KB, K0)                                                       \
  do {                                                                          \
    const int cb0 = (((q0 + w * 64) >> 5) - ((K0) >> 5) + 31) * 64 +            \
                    (ml - quad * 4 + 16);                                       \
    float tc[3][3][4];                                                          \
    _Pragma("unroll") for (int a = 0; a < 3; ++a)                               \
      _Pragma("unroll") for (int b = 0; b < 3; ++b) {                           \
        const int cb = cb0 + a * 64 + b * 16;                                   \
        _Pragma("unroll") for (int r = 0; r < 4; ++r)                           \
          tc[a][b][r] = toep[cb - r];                                           \
      }                                                                         \
    _Pragma("unroll") for (int nt = 0; nt < 4; ++nt) {                          \
      bf16x8 kf0 =                                                              \
          *(const bf16x8*)&Ks[KB][nt * 16 + ml][(quad ^ (ml & 7)) * 8];         \
      bf16x8 kf1 =                                                              \
          *(const bf16x8*)&Ks[KB][nt * 16 + ml][((4 + quad) ^ (ml & 7)) * 8];   \
      s16x4 pfrag[4];                                                           \
      _Pragma("unroll") for (int qn = 0; qn < 4; ++qn) {                        \
        f32x4 z = (f32x4){0.f, 0.f, 0.f, 0.f};                                  \
        z = __builtin_amdgcn_mfma_f32_16x16x32_bf16(kf0, qf[qn][0], z, 0,0,0);  \
        z = __builtin_amdgcn_mfma_f32_16x16x32_bf16(kf1, qf[qn][1], z, 0,0,0);  \
        float p[4];                                                             \
        _Pragma("unroll") for (int r = 0; r < 4; ++r)                           \
          p[r] = exp2f(fmaf(z[r], 0.18033688f,                                  \
                            tc[(qn >> 1) - (nt >> 1) + 1]                       \
                              [(qn & 1) - (nt & 1) + 1][r]));                   \
        lpart[qn] += (p[0] + p[1]) + (p[2] + p[3]);                             \
        bf16x4 pk;                                                              \
        _Pragma("unroll") for (int r = 0; r < 4; ++r) pk[r] = (__bf16)p[r];     \
        pfrag[qn] = __builtin_bit_cast(s16x4, pk);                              \
      }                                                                         \
      _Pragma("unroll") for (int dt = 0; dt < 4; ++dt) {                        \
        int row = dt * 16 + ml;                                                 \
        int gc = nt * 2 + (quad >> 1);                                          \
        bf16x4 vfr = *(const bf16x4*)                                           \
            &Vs[KB][row][((gc ^ (row & 7)) * 8) + (quad & 1) * 4];              \
        s16x4 vfs = __builtin_bit_cast(s16x4, vfr);                             \
        _Pragma("unroll") for (int qn = 0; qn < 4; ++qn)                        \
          o[qn][dt] = __builtin_amdgcn_mfma_f32_16x16x16bf16_1k(                \
              pfrag[qn], vfs, o[qn][dt], 0, 0, 0);                              \
      }                                                                         \
    }                                                                           \
  } while (0)

  int bcur = 0, bst = 2;
  for (int tt = 0; tt < 15; ++tt) {
    // tile tt's 4 DMAs done (only tile tt+1's 4 remain); toep writes flushed
    WAIT_VM_LG(4);
    BARRIER();  // buf[bcur] visible to all; buf[bst] overwrite-safe
    if (tt < 14) KV_STAGE(bst, (tt + 2) << 6);
    ATTN_TILE(bcur, tt << 6);
    bcur = (bcur == 2) ? 0 : bcur + 1;
    bst = (bst == 2) ? 0 : bst + 1;
  }
  WAIT_VM_LG(0);
  BARRIER();
  ATTN_TILE(bcur, 15 << 6);
#undef ATTN_TILE
#undef KV_STAGE

  // ---- softmax denominators (per qn: sum the 4 quads sharing q=ml) ----
#pragma unroll
  for (int qn = 0; qn < 4; ++qn) {
    lpart[qn] += __shfl_xor(lpart[qn], 16);
    lpart[qn] += __shfl_xor(lpart[qn], 32);
  }
  float linv[4][4];
#pragma unroll
  for (int qn = 0; qn < 4; ++qn)
#pragma unroll
    for (int r = 0; r < 4; ++r)
      linv[qn][r] = 1.0f / __shfl(lpart[qn], quad * 16 + quad * 4 + r);

  // ---- epilogue: rows q = q0 + w*64 + qn*16 + quad*4 + r, cols dt*16+ml ----
#pragma unroll
  for (int qn = 0; qn < 4; ++qn)
#pragma unroll
    for (int dt = 0; dt < 4; ++dt)
#pragma unroll
      for (int r = 0; r < 4; ++r) {
        int row = q0 + w * 64 + qn * 16 + quad * 4 + r;
        xg[((size_t)(bh >> 3) * L_ + row) * 512 + h * 64 + dt * 16 + ml] =
            (__bf16)(o[qn][dt][r] * linv[qn][r]);
      }
}

// ---------------------------------------------------------------------------
// Output GEMM: out[16384,512] (fp32) = Xattn(bf16) @ Wo + bo.
// Triple-buffered, prefetch distance 2, counted vmcnt (4 DMA/wave/tile).
// ---------------------------------------------------------------------------
__global__ __launch_bounds__(256, 2) void gemm_out_kernel(
    const __bf16* __restrict__ Xb,
    const __bf16* __restrict__ Wt,
    const float* __restrict__ bo,
    float* __restrict__ out)
{
  __shared__ __align__(16) __bf16 As[3][4][128][8];  // 24 KB
  __shared__ __align__(16) __bf16 Bs[3][4][128][8];  // 24 KB
  const int t = threadIdx.x;
  const int m0 = blockIdx.x * 128, n0 = blockIdx.y * 128;
  const int lane = t & 63, w = t >> 6;
  const int ml = lane & 15, quad = lane >> 4;
  const int wm = w & 1, wn = w >> 1;

  f32x4 acc[4][4];
#pragma unroll
  for (int i = 0; i < 4; ++i)
#pragma unroll
    for (int j = 0; j < 4; ++j) acc[i][j] = (f32x4){0.f, 0.f, 0.f, 0.f};

  const int slot0 = w * 64 + lane;
  const int slot1 = (w + 4) * 64 + lane;
  const int ko0 = slot0 >> 7, row0_ = slot0 & 127;
  const int ko1 = slot1 >> 7, row1_ = slot1 & 127;

#define STAGE_OUT(buf, kk)                                                      \
  do {                                                                          \
    gl_lds16(&Xb[(size_t)(m0 + row0_) * 512 + (kk) + ko0 * 8],                  \
             &As[buf][ko0][row0_][0]);                                          \
    gl_lds16(&Wt[(size_t)(n0 + row0_) * 512 + (kk) + ko0 * 8],                  \
             &Bs[buf][ko0][row0_][0]);                                          \
    gl_lds16(&Xb[(size_t)(m0 + row1_) * 512 + (kk) + ko1 * 8],                  \
             &As[buf][ko1][row1_][0]);                                          \
    gl_lds16(&Wt[(size_t)(n0 + row1_) * 512 + (kk) + ko1 * 8],                  \
             &Bs[buf][ko1][row1_][0]);                                          \
  } while (0)

#define COMPUTE_TILE_O(buf)                                                     \
  do {                                                                          \
    bf16x8 a[4], b[4];                                                          \
    _Pragma("unroll") for (int mt = 0; mt < 4; ++mt)                            \
        a[mt] = *(const bf16x8*)&As[buf][quad][wm * 64 + mt * 16 + ml][0];      \
    _Pragma("unroll") for (int nt = 0; nt < 4; ++nt)                            \
        b[nt] = *(const bf16x8*)&Bs[buf][quad][wn * 64 + nt * 16 + ml][0];      \
    _Pragma("unroll") for (int mt = 0; mt < 4; ++mt)                            \
        _Pragma("unroll") for (int nt = 0; nt < 4; ++nt)                        \
            acc[mt][nt] = __builtin_amdgcn_mfma_f32_16x16x32_bf16(              \
                a[mt], b[nt], acc[mt][nt], 0, 0, 0);                            \
  } while (0)

  STAGE_OUT(0, 0);
  STAGE_OUT(1, 32);

  int bcur = 0, bst = 2;
  for (int tt = 0; tt < 15; ++tt) {
    WAIT_VM_LG(4);   // tile tt's 4 DMAs done; tile tt+1's stay in flight
    BARRIER();
    if (tt < 14) STAGE_OUT(bst, (tt + 2) * 32);
    COMPUTE_TILE_O(bcur);
    bcur = (bcur == 2) ? 0 : bcur + 1;
    bst = (bst == 2) ? 0 : bst + 1;
  }
  WAIT_VM_LG(0);
  BARRIER();
  COMPUTE_TILE_O(bcur);

#pragma unroll
  for (int nt = 0; nt < 4; ++nt) {
    int col = n0 + wn * 64 + nt * 16 + ml;
    float bv = bo[col];
#pragma unroll
    for (int mt = 0; mt < 4; ++mt) {
      int row0 = m0 + wm * 64 + mt * 16 + quad * 4;
#pragma unroll
      for (int r = 0; r < 4; ++r)
        out[(size_t)(row0 + r) * 512 + col] = acc[mt][nt][r] + bv;
    }
  }
#undef STAGE_OUT
#undef COMPUTE_TILE_O
}

// ---------------------------------------------------------------------------
extern "C" void kernel_launch(void* const* d_in, const int* in_sizes, int n_in,
                              void* d_out, int out_size, void* d_ws, size_t ws_size,
                              hipStream_t stream) {
  const float* inputs_q  = (const float*)d_in[0];
  const float* inputs_kv = (const float*)d_in[1];
  const float* Wq = (const float*)d_in[2];
  const float* bq = (const float*)d_in[3];
  const float* Wk = (const float*)d_in[4];
  const float* bk = (const float*)d_in[5];
  const float* Wv = (const float*)d_in[6];
  const float* bv = (const float*)d_in[7];
  const float* Wo = (const float*)d_in[8];
  const float* bo = (const float*)d_in[9];
  const float* toep = (const float*)d_in[10];
  float* out = (float*)d_out;

  char* ws = (char*)d_ws;
  __bf16* qb  = (__bf16*)(ws);                  // 16 MB
  __bf16* kb  = (__bf16*)(ws + 16777216);       // 16 MB
  __bf16* vb  = (__bf16*)(ws + 33554432);       // 16 MB
  __bf16* xb  = (__bf16*)(ws + 50331648);       // 16 MB (attn out)
  __bf16* Wt  = (__bf16*)(ws + 67108864);       // 2 MB

  wt_kernel<<<dim3(16, 16, 4), 256, 0, stream>>>(Wq, Wk, Wv, Wo, Wt);
  // proj split into two dispatches (diagnostic: surfaces attn/out in top-5)
  gemm_proj_kernel<<<dim3(128, 6), 256, 0, stream>>>(
      inputs_q, inputs_kv, Wt, bq, bk, bv, qb, kb, vb, 0);
  gemm_proj_kernel<<<dim3(128, 6), 256, 0, stream>>>(
      inputs_q, inputs_kv, Wt, bq, bk, bv, qb, kb, vb, 6);
  attn_kernel<<<dim3(512), 256, 0, stream>>>(qb, kb, vb, toep, xb);
  gemm_out_kernel<<<dim3(128, 4), 256, 0, stream>>>(xb, Wt + 3 * 262144, bo, out);
}

// Round 7
// 258.484 us; speedup vs baseline: 1.0547x; 1.0547x over previous
//
#include <hip/hip_runtime.h>
#include <hip/hip_bf16.h>

// Problem constants
#define B_  16
#define L_  1024
#define F_  512
#define H_  8
#define D_  64
#define M_  (B_ * L_)    // 16384 rows
#define HD_ 512

typedef __bf16 bf16x8 __attribute__((ext_vector_type(8)));
typedef __bf16 bf16x4 __attribute__((ext_vector_type(4)));
typedef short  s16x4  __attribute__((ext_vector_type(4)));
typedef float  f32x4  __attribute__((ext_vector_type(4)));

// Async global->LDS, 16B per lane. LDS dest must be wave-uniform base + lane*16.
__device__ __forceinline__ void gl_lds16(const void* g, void* l) {
  __builtin_amdgcn_global_load_lds(
      (const __attribute__((address_space(1))) unsigned int*)g,
      (__attribute__((address_space(3))) unsigned int*)l, 16, 0, 0);
}

// Raw v_exp_f32: computes 2^x (one TRANS op; exp2f libm adds guard code).
__device__ __forceinline__ float exp2_fast(float x) {
  float r;
  asm("v_exp_f32 %0, %1" : "=v"(r) : "v"(x));
  return r;
}

#define WAIT_VM_LG(N)                                                           \
  asm volatile("s_waitcnt vmcnt(" #N ") lgkmcnt(0)" ::: "memory")
#define BARRIER() asm volatile("s_barrier" ::: "memory")

// Q pre-scale: 0.125 (1/sqrt(D)) * log2(e), folded into proj epilogue so the
// attn inner loop is a plain v_add + v_exp per S-element.
#define QSCALE 0.18033688f
#define LOG2E  1.44269504f

// ---------------------------------------------------------------------------
// Weight prep: Wt[n][k] = (bf16) W[k][n]  for Wq,Wk,Wv,Wo (each 512x512).
// ---------------------------------------------------------------------------
__global__ __launch_bounds__(256) void wt_kernel(
    const float* __restrict__ Wq, const float* __restrict__ Wk,
    const float* __restrict__ Wv, const float* __restrict__ Wo,
    __bf16* __restrict__ Wt_all)
{
  const float* W = (blockIdx.z == 0) ? Wq : (blockIdx.z == 1) ? Wk
                 : (blockIdx.z == 2) ? Wv : Wo;
  __bf16* Wt = Wt_all + (size_t)blockIdx.z * (512 * 512);
  __shared__ float s[32][33];
  const int t = threadIdx.x;
  const int r = t >> 5, c = t & 31;
  const int k0 = blockIdx.x * 32, n0 = blockIdx.y * 32;
#pragma unroll
  for (int i = 0; i < 4; ++i)
    s[r + i * 8][c] = W[(size_t)(k0 + r + i * 8) * 512 + n0 + c];
  __syncthreads();
#pragma unroll
  for (int i = 0; i < 4; ++i)
    Wt[(size_t)(n0 + r + i * 8) * 512 + k0 + c] = (__bf16)s[c][r + i * 8];
}

// ---------------------------------------------------------------------------
// Merged projection GEMM (q, k, v). 128x128 tile, 256 thr.
// A: fp32 load->reg (distance 1) -> convert -> ds_write (double-buffered).
// B: async DMA, triple-buffered, prefetch distance 2, counted vmcnt.
// seg 0 output is pre-scaled by QSCALE (softmax scale folded in).
// grid (128, 12): seg = by>>2 (0 q, 1 k, 2 v); n0 = (by&3)*128.
// seg 0/1 dst (B,H,L,D); seg 2 dst (B,H,D,L).
// ---------------------------------------------------------------------------
__global__ __launch_bounds__(256) void gemm_proj_kernel(
    const float* __restrict__ Xq, const float* __restrict__ Xkv,
    const __bf16* __restrict__ Wt_all,
    const float* __restrict__ bq, const float* __restrict__ bk_,
    const float* __restrict__ bv_,
    __bf16* __restrict__ qd, __bf16* __restrict__ kd, __bf16* __restrict__ vd)
{
  const int by = blockIdx.y;
  const int seg = by >> 2;
  const float* X = (seg == 0) ? Xq : Xkv;
  const __bf16* Wt = Wt_all + (size_t)seg * 262144;
  const float* bias = (seg == 0) ? bq : (seg == 1) ? bk_ : bv_;
  __bf16* dst = (seg == 0) ? qd : (seg == 1) ? kd : vd;
  const int mode = seg;
  const float oscale = (seg == 0) ? QSCALE : 1.0f;

  __shared__ __align__(16) __bf16 As[2][4][128][8];  // 16 KB
  __shared__ __align__(16) __bf16 Bs[3][4][128][8];  // 24 KB
  const int t = threadIdx.x;
  const int m0 = blockIdx.x * 128, n0 = (by & 3) * 128;
  const int lane = t & 63, w = t >> 6;
  const int ml = lane & 15, quad = lane >> 4;
  const int wm = w & 1, wn = w >> 1;

  f32x4 acc[4][4];
#pragma unroll
  for (int i = 0; i < 4; ++i)
#pragma unroll
    for (int j = 0; j < 4; ++j) acc[i][j] = (f32x4){0.f, 0.f, 0.f, 0.f};

  const int ako0 = t & 3,          arow0 = t >> 2;
  const int ako1 = (t + 256) & 3,  arow1 = (t + 256) >> 2;
  const int bs0 = w * 64 + lane,   bs1 = (w + 4) * 64 + lane;
  const int bko0 = bs0 >> 7, brow0 = bs0 & 127;
  const int bko1 = bs1 >> 7, brow1 = bs1 & 127;

  float4 fa0, fa1, fa2, fa3;  // A prefetch registers (16 fp32)

#define ALOAD(kk)                                                               \
  do {                                                                          \
    const float* p0 = X + (size_t)(m0 + arow0) * 512 + (kk) + ako0 * 8;         \
    const float* p1 = X + (size_t)(m0 + arow1) * 512 + (kk) + ako1 * 8;         \
    fa0 = *(const float4*)p0; fa1 = *(const float4*)(p0 + 4);                   \
    fa2 = *(const float4*)p1; fa3 = *(const float4*)(p1 + 4);                   \
  } while (0)

#define AWRITE(buf)                                                             \
  do {                                                                          \
    bf16x8 v0, v1;                                                              \
    v0[0] = (__bf16)fa0.x; v0[1] = (__bf16)fa0.y; v0[2] = (__bf16)fa0.z;        \
    v0[3] = (__bf16)fa0.w; v0[4] = (__bf16)fa1.x; v0[5] = (__bf16)fa1.y;        \
    v0[6] = (__bf16)fa1.z; v0[7] = (__bf16)fa1.w;                               \
    v1[0] = (__bf16)fa2.x; v1[1] = (__bf16)fa2.y; v1[2] = (__bf16)fa2.z;        \
    v1[3] = (__bf16)fa2.w; v1[4] = (__bf16)fa3.x; v1[5] = (__bf16)fa3.y;        \
    v1[6] = (__bf16)fa3.z; v1[7] = (__bf16)fa3.w;                               \
    *(bf16x8*)&As[buf][ako0][arow0][0] = v0;                                    \
    *(bf16x8*)&As[buf][ako1][arow1][0] = v1;                                    \
  } while (0)

#define BSTAGE(buf, kk)                                                         \
  do {                                                                          \
    gl_lds16(&Wt[(size_t)(n0 + brow0) * 512 + (kk) + bko0 * 8],                 \
             &Bs[buf][bko0][brow0][0]);                                         \
    gl_lds16(&Wt[(size_t)(n0 + brow1) * 512 + (kk) + bko1 * 8],                 \
             &Bs[buf][bko1][brow1][0]);                                         \
  } while (0)

#define COMPUTE_TILE(ab, bb)                                                    \
  do {                                                                          \
    bf16x8 a[4], b[4];                                                          \
    _Pragma("unroll") for (int mt = 0; mt < 4; ++mt)                            \
        a[mt] = *(const bf16x8*)&As[ab][quad][wm * 64 + mt * 16 + ml][0];       \
    _Pragma("unroll") for (int nt = 0; nt < 4; ++nt)                            \
        b[nt] = *(const bf16x8*)&Bs[bb][quad][wn * 64 + nt * 16 + ml][0];       \
    _Pragma("unroll") for (int mt = 0; mt < 4; ++mt)                            \
        _Pragma("unroll") for (int nt = 0; nt < 4; ++nt)                        \
            acc[mt][nt] = __builtin_amdgcn_mfma_f32_16x16x32_bf16(              \
                a[mt], b[nt], acc[mt][nt], 0, 0, 0);                            \
  } while (0)

  ALOAD(0);
  BSTAGE(0, 0);
  BSTAGE(1, 32);
  AWRITE(0);
  WAIT_VM_LG(2);
  BARRIER();

  int bcur = 0, bst = 2;
  for (int tt = 0; tt < 16; ++tt) {
    if (tt < 15) ALOAD((tt + 1) * 32);
    if (tt < 14) BSTAGE(bst, (tt + 2) * 32);
    COMPUTE_TILE(tt & 1, bcur);
    if (tt < 14) {
      WAIT_VM_LG(2);
      AWRITE((tt + 1) & 1);
      asm volatile("s_waitcnt lgkmcnt(0)" ::: "memory");
      BARRIER();
    } else if (tt == 14) {
      WAIT_VM_LG(0);
      AWRITE((tt + 1) & 1);
      asm volatile("s_waitcnt lgkmcnt(0)" ::: "memory");
      BARRIER();
    }
    bcur = (bcur == 2) ? 0 : bcur + 1;
    bst = (bst == 2) ? 0 : bst + 1;
  }

#pragma unroll
  for (int nt = 0; nt < 4; ++nt) {
    int col = n0 + wn * 64 + nt * 16 + ml;
    float bv = bias[col];
    int h = col >> 6, d = col & 63;
#pragma unroll
    for (int mt = 0; mt < 4; ++mt) {
      int row0 = m0 + wm * 64 + mt * 16 + quad * 4;
      int bz = row0 >> 10;
      int l0 = row0 & 1023;
      if (mode == 2) {
        bf16x4 pk;
#pragma unroll
        for (int r = 0; r < 4; ++r) pk[r] = (__bf16)(acc[mt][nt][r] + bv);
        size_t idx = ((size_t)(bz * H_ + h) * D_ + d) * L_ + l0;
        *(bf16x4*)&dst[idx] = pk;
      } else {
        size_t base = ((size_t)(bz * H_ + h) * L_ + l0) * D_ + d;
#pragma unroll
        for (int r = 0; r < 4; ++r)
          dst[base + (size_t)r * D_] = (__bf16)((acc[mt][nt][r] + bv) * oscale);
      }
    }
  }
#undef ALOAD
#undef AWRITE
#undef BSTAGE
#undef COMPUTE_TILE
}

// ---------------------------------------------------------------------------
// Flash attention v8 = v6 base (double-buffered K/V, __syncthreads; measured
// 64us) + VALU deletion:
//  - Q pre-scaled by QSCALE in proj, toep pre-scaled by log2e at staging ->
//    inner S-element is v_add + raw v_exp_f32 (no fmaf/mul, no libm exp2f).
//  - softmax denominators via MFMA row-sum: mfma(pfrag, ones, acc_l) per
//    (nt,qn). acc_l's C layout (row=quad*4+r) matches the epilogue row map
//    exactly, so the end shuffle-reduction is deleted too.
// ---------------------------------------------------------------------------
__global__ __launch_bounds__(256, 2) void attn_kernel(
    const __bf16* __restrict__ qg,    // [B][H][L][D] (pre-scaled by QSCALE)
    const __bf16* __restrict__ kg,    // [B][H][L][D]
    const __bf16* __restrict__ vg,    // [B][H][D][L]
    const float* __restrict__ toep_g, // [H][4096]
    __bf16* __restrict__ xg)          // [B*L][512]
{
  __shared__ float toep[4096];                   // 16 KB (pre-scaled by log2e)
  __shared__ __align__(16) __bf16 Ks[2][64][64]; // 2 x 8 KB (swizzled)
  __shared__ __align__(16) __bf16 Vs[2][64][64]; // 2 x 8 KB (swizzled)

  const int t = threadIdx.x;
  const int n = blockIdx.x;
  // XCD swizzle: the 4 q-tiles sharing one (b,h) land on the same XCD.
  const int bh = ((n >> 5) << 3) | (n & 7);
  const int q0 = ((n >> 3) & 3) * 256;
  const int h = bh & 7;
  const int lane = t & 63, w = t >> 6;
  const int ml = lane & 15, quad = lane >> 4;
  const int lo3 = lane >> 3;        // 0..7 (== row&7 for staging rows)
  const int kop = lane & 7;         // LDS 16B-chunk slot

  const size_t qkbase = (size_t)bh * (L_ * D_);
  const size_t vbase  = (size_t)bh * (D_ * L_);

  // toeplitz table -> LDS, pre-multiplied by log2(e) for the exp2 path
  {
    const float4* src = (const float4*)(toep_g + (size_t)h * 4096);
    float4* dl = (float4*)toep;
    for (int i = t; i < 1024; i += 256) {
      float4 v = src[i];
      v.x *= LOG2E; v.y *= LOG2E; v.z *= LOG2E; v.w *= LOG2E;
      dl[i] = v;
    }
  }

  // stage K,V tile 0 (coalesced swizzled DMA)
#pragma unroll
  for (int i = 0; i < 2; ++i) {
    int row = (w * 2 + i) * 8 + lo3;
    int ko = kop ^ lo3;
    gl_lds16(&kg[qkbase + (size_t)row * D_ + ko * 8], &Ks[0][row][kop * 8]);
    gl_lds16(&vg[vbase + (size_t)row * L_ + ko * 8], &Vs[0][row][kop * 8]);
  }

  // Q B-fragments, 4 q-subtiles, registers for the whole kernel (32 VGPR)
  bf16x8 qf[4][2];
#pragma unroll
  for (int qn = 0; qn < 4; ++qn) {
    const __bf16* qp =
        qg + qkbase + (size_t)(q0 + w * 64 + qn * 16 + ml) * D_ + quad * 8;
    qf[qn][0] = *(const bf16x8*)qp;
    qf[qn][1] = *(const bf16x8*)(qp + 32);
  }

  // ones operand for the MFMA row-sum (bf16 1.0 = 0x3F80)
  const s16x4 ones = {(short)0x3F80, (short)0x3F80, (short)0x3F80, (short)0x3F80};

  f32x4 acc_l[4];   // running P row-sums; C-layout row = quad*4+r
  f32x4 o[4][4];
#pragma unroll
  for (int qn = 0; qn < 4; ++qn) {
    acc_l[qn] = (f32x4){0.f, 0.f, 0.f, 0.f};
#pragma unroll
    for (int dt = 0; dt < 4; ++dt) o[qn][dt] = (f32x4){0.f, 0.f, 0.f, 0.f};
  }

  __syncthreads();  // toep + tile 0 ready (barrier drains vmcnt)

  int cur = 0;
  for (int k0 = 0; k0 < L_; k0 += 64) {
    // ---- stage NEXT K,V tile (async, consumed after the end barrier) ----
    if (k0 + 64 < L_) {
      int nb = cur ^ 1;
#pragma unroll
      for (int i = 0; i < 2; ++i) {
        int row = (w * 2 + i) * 8 + lo3;
        int ko = kop ^ lo3;
        gl_lds16(&kg[qkbase + (size_t)(k0 + 64 + row) * D_ + ko * 8],
                 &Ks[nb][row][kop * 8]);
        gl_lds16(&vg[vbase + (size_t)row * L_ + k0 + 64 + ko * 8],
                 &Vs[nb][row][kop * 8]);
      }
    }

    // ---- per-tile toeplitz register cache (9 cells x 4) ----
    const int cb0 = (((q0 + w * 64) >> 5) - (k0 >> 5) + 31) * 64 +
                    (ml - quad * 4 + 16);
    float tc[3][3][4];
#pragma unroll
    for (int a = 0; a < 3; ++a)
#pragma unroll
      for (int b = 0; b < 3; ++b) {
        const int cb = cb0 + a * 64 + b * 16;
#pragma unroll
        for (int r = 0; r < 4; ++r) tc[a][b][r] = toep[cb - r];
      }

    // ---- per 16-key group: S^T -> bias+exp2 -> P frag (regs) -> PV ----
#pragma unroll
    for (int nt = 0; nt < 4; ++nt) {
      bf16x8 kf0 = *(const bf16x8*)&Ks[cur][nt * 16 + ml][(quad ^ (ml & 7)) * 8];
      bf16x8 kf1 =
          *(const bf16x8*)&Ks[cur][nt * 16 + ml][((4 + quad) ^ (ml & 7)) * 8];

      s16x4 pfrag[4];
#pragma unroll
      for (int qn = 0; qn < 4; ++qn) {
        f32x4 z = (f32x4){0.f, 0.f, 0.f, 0.f};
        z = __builtin_amdgcn_mfma_f32_16x16x32_bf16(kf0, qf[qn][0], z, 0, 0, 0);
        z = __builtin_amdgcn_mfma_f32_16x16x32_bf16(kf1, qf[qn][1], z, 0, 0, 0);

        float p[4];
#pragma unroll
        for (int r = 0; r < 4; ++r)
          p[r] = exp2_fast(z[r] + tc[(qn >> 1) - (nt >> 1) + 1]
                                    [(qn & 1) - (nt & 1) + 1][r]);
        bf16x4 pk;
#pragma unroll
        for (int r = 0; r < 4; ++r) pk[r] = (__bf16)p[r];
        pfrag[qn] = __builtin_bit_cast(s16x4, pk);
        // running denominator: rowsum of P via matrix pipe (replaces VALU adds)
        acc_l[qn] = __builtin_amdgcn_mfma_f32_16x16x16bf16_1k(
            pfrag[qn], ones, acc_l[qn], 0, 0, 0);
      }

      // PV for this 16-key group: K=16 MFMA, A=pfrag (regs), B=V b64 frags
#pragma unroll
      for (int dt = 0; dt < 4; ++dt) {
        int row = dt * 16 + ml;
        int gc = nt * 2 + (quad >> 1);
        bf16x4 vfr = *(const bf16x4*)
            &Vs[cur][row][((gc ^ (row & 7)) * 8) + (quad & 1) * 4];
        s16x4 vfs = __builtin_bit_cast(s16x4, vfr);
#pragma unroll
        for (int qn = 0; qn < 4; ++qn)
          o[qn][dt] = __builtin_amdgcn_mfma_f32_16x16x16bf16_1k(
              pfrag[qn], vfs, o[qn][dt], 0, 0, 0);
      }
    }

    __syncthreads();  // next tile staged + all reads of cur done
    cur ^= 1;
  }

  // ---- denominators are already per-thread in the right layout ----
  float linv[4][4];
#pragma unroll
  for (int qn = 0; qn < 4; ++qn)
#pragma unroll
    for (int r = 0; r < 4; ++r)
      linv[qn][r] = 1.0f / acc_l[qn][r];

  // ---- epilogue: rows q = q0 + w*64 + qn*16 + quad*4 + r, cols dt*16+ml ----
#pragma unroll
  for (int qn = 0; qn < 4; ++qn)
#pragma unroll
    for (int dt = 0; dt < 4; ++dt)
#pragma unroll
      for (int r = 0; r < 4; ++r) {
        int row = q0 + w * 64 + qn * 16 + quad * 4 + r;
        xg[((size_t)(bh >> 3) * L_ + row) * 512 + h * 64 + dt * 16 + ml] =
            (__bf16)(o[qn][dt][r] * linv[qn][r]);
      }
}

// ---------------------------------------------------------------------------
// Output GEMM: out[16384,512] (fp32) = Xattn(bf16) @ Wo + bo.
// Triple-buffered, prefetch distance 2, counted vmcnt (4 DMA/wave/tile).
// ---------------------------------------------------------------------------
__global__ __launch_bounds__(256, 2) void gemm_out_kernel(
    const __bf16* __restrict__ Xb,
    const __bf16* __restrict__ Wt,
    const float* __restrict__ bo,
    float* __restrict__ out)
{
  __shared__ __align__(16) __bf16 As[3][4][128][8];  // 24 KB
  __shared__ __align__(16) __bf16 Bs[3][4][128][8];  // 24 KB
  const int t = threadIdx.x;
  const int m0 = blockIdx.x * 128, n0 = blockIdx.y * 128;
  const int lane = t & 63, w = t >> 6;
  const int ml = lane & 15, quad = lane >> 4;
  const int wm = w & 1, wn = w >> 1;

  f32x4 acc[4][4];
#pragma unroll
  for (int i = 0; i < 4; ++i)
#pragma unroll
    for (int j = 0; j < 4; ++j) acc[i][j] = (f32x4){0.f, 0.f, 0.f, 0.f};

  const int slot0 = w * 64 + lane;
  const int slot1 = (w + 4) * 64 + lane;
  const int ko0 = slot0 >> 7, row0_ = slot0 & 127;
  const int ko1 = slot1 >> 7, row1_ = slot1 & 127;

#define STAGE_OUT(buf, kk)                                                      \
  do {                                                                          \
    gl_lds16(&Xb[(size_t)(m0 + row0_) * 512 + (kk) + ko0 * 8],                  \
             &As[buf][ko0][row0_][0]);                                          \
    gl_lds16(&Wt[(size_t)(n0 + row0_) * 512 + (kk) + ko0 * 8],                  \
             &Bs[buf][ko0][row0_][0]);                                          \
    gl_lds16(&Xb[(size_t)(m0 + row1_) * 512 + (kk) + ko1 * 8],                  \
             &As[buf][ko1][row1_][0]);                                          \
    gl_lds16(&Wt[(size_t)(n0 + row1_) * 512 + (kk) + ko1 * 8],                  \
             &Bs[buf][ko1][row1_][0]);                                          \
  } while (0)

#define COMPUTE_TILE_O(buf)                                                     \
  do {                                                                          \
    bf16x8 a[4], b[4];                                                          \
    _Pragma("unroll") for (int mt = 0; mt < 4; ++mt)                            \
        a[mt] = *(const bf16x8*)&As[buf][quad][wm * 64 + mt * 16 + ml][0];      \
    _Pragma("unroll") for (int nt = 0; nt < 4; ++nt)                            \
        b[nt] = *(const bf16x8*)&Bs[buf][quad][wn * 64 + nt * 16 + ml][0];      \
    _Pragma("unroll") for (int mt = 0; mt < 4; ++mt)                            \
        _Pragma("unroll") for (int nt = 0; nt < 4; ++nt)                        \
            acc[mt][nt] = __builtin_amdgcn_mfma_f32_16x16x32_bf16(              \
                a[mt], b[nt], acc[mt][nt], 0, 0, 0);                            \
  } while (0)

  STAGE_OUT(0, 0);
  STAGE_OUT(1, 32);

  int bcur = 0, bst = 2;
  for (int tt = 0; tt < 15; ++tt) {
    WAIT_VM_LG(4);   // tile tt's 4 DMAs done; tile tt+1's stay in flight
    BARRIER();
    if (tt < 14) STAGE_OUT(bst, (tt + 2) * 32);
    COMPUTE_TILE_O(bcur);
    bcur = (bcur == 2) ? 0 : bcur + 1;
    bst = (bst == 2) ? 0 : bst + 1;
  }
  WAIT_VM_LG(0);
  BARRIER();
  COMPUTE_TILE_O(bcur);

#pragma unroll
  for (int nt = 0; nt < 4; ++nt) {
    int col = n0 + wn * 64 + nt * 16 + ml;
    float bv = bo[col];
#pragma unroll
    for (int mt = 0; mt < 4; ++mt) {
      int row0 = m0 + wm * 64 + mt * 16 + quad * 4;
#pragma unroll
      for (int r = 0; r < 4; ++r)
        out[(size_t)(row0 + r) * 512 + col] = acc[mt][nt][r] + bv;
    }
  }
#undef STAGE_OUT
#undef COMPUTE_TILE_O
}

// ---------------------------------------------------------------------------
extern "C" void kernel_launch(void* const* d_in, const int* in_sizes, int n_in,
                              void* d_out, int out_size, void* d_ws, size_t ws_size,
                              hipStream_t stream) {
  const float* inputs_q  = (const float*)d_in[0];
  const float* inputs_kv = (const float*)d_in[1];
  const float* Wq = (const float*)d_in[2];
  const float* bq = (const float*)d_in[3];
  const float* Wk = (const float*)d_in[4];
  const float* bk = (const float*)d_in[5];
  const float* Wv = (const float*)d_in[6];
  const float* bv = (const float*)d_in[7];
  const float* Wo = (const float*)d_in[8];
  const float* bo = (const float*)d_in[9];
  const float* toep = (const float*)d_in[10];
  float* out = (float*)d_out;

  char* ws = (char*)d_ws;
  __bf16* qb  = (__bf16*)(ws);                  // 16 MB
  __bf16* kb  = (__bf16*)(ws + 16777216);       // 16 MB
  __bf16* vb  = (__bf16*)(ws + 33554432);       // 16 MB
  __bf16* xb  = (__bf16*)(ws + 50331648);       // 16 MB (attn out)
  __bf16* Wt  = (__bf16*)(ws + 67108864);       // 2 MB

  wt_kernel<<<dim3(16, 16, 4), 256, 0, stream>>>(Wq, Wk, Wv, Wo, Wt);
  gemm_proj_kernel<<<dim3(128, 12), 256, 0, stream>>>(
      inputs_q, inputs_kv, Wt, bq, bk, bv, qb, kb, vb);
  attn_kernel<<<dim3(512), 256, 0, stream>>>(qb, kb, vb, toep, xb);
  gemm_out_kernel<<<dim3(128, 4), 256, 0, stream>>>(xb, Wt + 3 * 262144, bo, out);
}